// Round 1
// baseline (4995.869 us; speedup 1.0000x reference)
//
#include <hip/hip_runtime.h>
#include <cmath>
#include <algorithm>

#define N_NODES 8192
#define N_EDGES 131072
#define NPATHS 15
#define FPN 576          // floats per node: 64 (l0) + 192 (l1) + 320 (l2)

// path table: (l1, l2, l3) in python enumeration order
constexpr int PL1[NPATHS] = {0,0,0,1,1,1,1,1,1,2,2,2,2,2,2};
constexpr int PL2[NPATHS] = {0,1,2,0,1,1,1,2,2,0,1,1,2,2,2};
constexpr int PL3[NPATHS] = {0,1,2,1,0,1,2,1,2,2,1,2,0,1,2};
constexpr int CGOFF[NPATHS] = {0,1,10,35,44,53,80,125,170,245,270,315,390,415,490};
constexpr int CGTOT = 615;
constexpr int BOFF[3] = {0,1,4};   // offsets of l-blocks inside 9-float (X/S/msg) arrays

struct CGTable { float v[CGTOT]; };

// ---------------- host-side CG construction (exact replica of reference) ----
namespace cgb {
struct C2 { double re, im; };
static inline C2 cmul(C2 a, C2 b){ return {a.re*b.re - a.im*b.im, a.re*b.im + a.im*b.re}; }
static double factd(int n){ double r=1.0; for (int i=2;i<=n;++i) r*=i; return r; }

static double cg_scalar(int j1,int m1,int j2,int m2,int j3,int m3){
  if (m1+m2 != m3) return 0.0;
  double pre = std::sqrt((2.0*j3+1.0)*factd(j1+j2-j3)*factd(j1-j2+j3)*factd(-j1+j2+j3)/factd(j1+j2+j3+1));
  pre *= std::sqrt(factd(j1+m1)*factd(j1-m1)*factd(j2+m2)*factd(j2-m2)*factd(j3+m3)*factd(j3-m3));
  double s = 0.0;
  int kmin = std::max(0, std::max(j2-j3-m1, j1+m2-j3));
  int kmax = std::min(j1+j2-j3, std::min(j1-m1, j2+m2));
  for (int k=kmin;k<=kmax;++k){
    double t = 1.0/(factd(k)*factd(j1+j2-j3-k)*factd(j1-m1-k)*factd(j2+m2-k)*factd(j3-j2+m1+k)*factd(j3-j1-m2+k));
    s += (k&1) ? -t : t;
  }
  return pre*s;
}

static void makeU(int l, C2 U[5][5]){
  double s2 = std::sqrt(0.5);
  for (int a=0;a<5;++a) for (int b=0;b<5;++b) U[a][b] = {0.0,0.0};
  for (int m=-l;m<=l;++m){
    if (m > 0){
      U[m+l][ m+l] = {((m&1)?-1.0:1.0)*s2, 0.0};
      U[m+l][-m+l] = {s2, 0.0};
    } else if (m == 0){
      U[l][l] = {1.0, 0.0};
    } else {
      U[m+l][ m+l] = {0.0, s2};
      U[m+l][-m+l] = {0.0, -((((-m)&1))?-1.0:1.0)*s2};
    }
  }
}
} // namespace cgb

static CGTable build_cg_table(){
  using namespace cgb;
  CGTable t{};
  for (int p=0;p<NPATHS;++p){
    int l1=PL1[p], l2=PL2[p], l3=PL3[p];
    int n1=2*l1+1, n2=2*l2+1, n3=2*l3+1;
    double Cc[5][5][5] = {};
    for (int i1=0;i1<n1;++i1) for (int i2=0;i2<n2;++i2){
      int m1=i1-l1, m2=i2-l2, m3=m1+m2;
      if (m3 >= -l3 && m3 <= l3) Cc[i1][i2][m3+l3] = cg_scalar(l1,m1,l2,m2,l3,m3);
    }
    C2 U1[5][5], U2[5][5], U3[5][5];
    makeU(l1,U1); makeU(l2,U2); makeU(l3,U3);
    double Wre[5][5][5]={}, Wim[5][5][5]={};
    for (int i=0;i<n1;++i) for (int j=0;j<n2;++j) for (int k=0;k<n3;++k){
      double are=0.0, aim=0.0;
      for (int a=0;a<n1;++a) for (int b=0;b<n2;++b){
        int m3 = (a-l1)+(b-l2);
        if (m3 < -l3 || m3 > l3) continue;
        double cv = Cc[a][b][m3+l3];
        if (cv == 0.0) continue;
        C2 u1c = {U1[i][a].re, -U1[i][a].im};
        C2 u2c = {U2[j][b].re, -U2[j][b].im};
        C2 tt = cmul(cmul(u1c, u2c), U3[k][m3+l3]);
        are += tt.re*cv; aim += tt.im*cv;
      }
      Wre[i][j][k]=are; Wim[i][j][k]=aim;
    }
    double nr=0.0, ni=0.0;
    for (int i=0;i<n1;++i) for (int j=0;j<n2;++j) for (int k=0;k<n3;++k){
      nr += Wre[i][j][k]*Wre[i][j][k]; ni += Wim[i][j][k]*Wim[i][j][k];
    }
    bool useRe = std::sqrt(nr) >= std::sqrt(ni);
    double nrm = std::sqrt(useRe ? nr : ni);
    double scale = std::sqrt((double)n3) / nrm;
    for (int i=0;i<n1;++i) for (int j=0;j<n2;++j) for (int k=0;k<n3;++k)
      t.v[CGOFF[p] + (i*n2+j)*n3 + k] =
        (float)((useRe ? Wre[i][j][k] : Wim[i][j][k]) * scale);
  }
  return t;
}

static const CGTable& cg_table(){ static CGTable t = build_cg_table(); return t; }

// ---------------- device helpers ----------------
__device__ __forceinline__ float siluf(float x){ return x / (1.0f + expf(-x)); }
__device__ __forceinline__ float sigmf(float x){ return 1.0f / (1.0f + expf(-x)); }

// ---------------- kernels ----------------
__global__ __launch_bounds__(64) void k_init(const int* __restrict__ species,
    const float* __restrict__ embed, const float* __restrict__ wproj,
    float* __restrict__ feats)
{
  const int n = blockIdx.x, c = threadIdx.x;
  const int sp = species[n];
  float acc = 0.f;
  #pragma unroll
  for (int q=0;q<32;++q) acc += embed[sp*32+q]*wproj[q*64+c];
  feats[n*FPN + c] = acc;
  #pragma unroll
  for (int j=0;j<8;++j) feats[n*FPN + 64 + j*64 + c] = 0.f;   // zero l1,l2
}

// 16 edges per block; 4 waves x 4 edges/wave; lane = channel
__global__ __launch_bounds__(256) void k_edge(
    const float* __restrict__ pos,
    const int* __restrict__ senders, const int* __restrict__ receivers,
    const float* __restrict__ w1, const float* __restrict__ b1,
    const float* __restrict__ w2, const float* __restrict__ b2,
    const float* __restrict__ w3,
    const float* __restrict__ feats, float* __restrict__ agg,
    const CGTable cg)
{
  __shared__ float s_h1[16*64];
  __shared__ float s_h2[16*64];
  __shared__ float s_w3[8*960];
  __shared__ float s_sh[16][8];
  __shared__ float s_cut[16];

  const int tid  = threadIdx.x;
  const int wave = tid >> 6;
  const int lane = tid & 63;
  const int ebase = blockIdx.x * 16;
  const float PI = 3.14159265358979323846f;

  // Phase A1: geometry + radial basis + MLP layer 1
  #pragma unroll
  for (int ee=0; ee<4; ++ee){
    const int slot = wave*4 + ee;
    const int e = ebase + slot;
    const int s = senders[e], r = receivers[e];
    float rx = (pos[r*3+0] - pos[s*3+0]) * 0.2f;
    float ry = (pos[r*3+1] - pos[s*3+1]) * 0.2f;
    float rz = (pos[r*3+2] - pos[s*3+2]) * 0.2f;
    float d  = sqrtf(rx*rx + ry*ry + rz*rz);
    float iv = 1.0f / fmaxf(d, 1e-6f);
    float x = rx*iv, y = ry*iv, z = rz*iv;
    if (lane == 0){
      const float s3   = 1.7320508075688772f;   // sqrt(3)
      const float s15  = 3.8729833462074170f;   // sqrt(15)
      const float s5h  = 1.1180339887498949f;   // sqrt(5)/2
      const float s15h = 1.9364916731037085f;   // sqrt(15)/2
      s_sh[slot][0] = s3*y;
      s_sh[slot][1] = s3*z;
      s_sh[slot][2] = s3*x;
      s_sh[slot][3] = s15*x*y;
      s_sh[slot][4] = s15*y*z;
      s_sh[slot][5] = s5h*(3.f*z*z - 1.f);
      s_sh[slot][6] = s15*x*z;
      s_sh[slot][7] = s15h*(x*x - y*y);
      float dc = fminf(fmaxf(d, 0.f), 1.f);
      s_cut[slot] = 0.5f*(cosf(PI*dc) + 1.f);
    }
    float xr = fminf(fmaxf(d, 1e-4f), 1.0f);
    float ixr = 1.0f/xr;
    float acc = b1[lane];
    #pragma unroll
    for (int q=0;q<8;++q){
      float bs = 1.4142135623730951f * sinf((float)(q+1)*PI*xr) * ixr;
      acc += bs * w1[q*64 + lane];
    }
    s_h1[slot*64 + lane] = siluf(acc);
  }
  __syncthreads();

  // Phase A2: MLP layer 2
  #pragma unroll
  for (int ee=0; ee<4; ++ee){
    const int slot = wave*4 + ee;
    float acc = b2[lane];
    #pragma unroll
    for (int k=0;k<64;++k) acc += s_h1[slot*64+k] * w2[k*64+lane];
    s_h2[slot*64+lane] = siluf(acc);
  }
  __syncthreads();

  // Phase B: wgt[p] = (h2 @ w3)[:, p*64+lane], w3 staged via LDS in 8-row chunks
  float wgt[NPATHS][4];
  #pragma unroll
  for (int p=0;p<NPATHS;++p){ wgt[p][0]=wgt[p][1]=wgt[p][2]=wgt[p][3]=0.f; }

  for (int kc=0;kc<8;++kc){
    #pragma unroll
    for (int rr=0;rr<8;++rr){
      #pragma unroll
      for (int jj=0;jj<4;++jj){
        int col = jj*256 + tid;
        if (col < 960) s_w3[rr*960+col] = w3[(kc*8+rr)*960+col];
      }
    }
    __syncthreads();
    #pragma unroll
    for (int kk=0;kk<8;++kk){
      float h2v[4];
      #pragma unroll
      for (int ee=0;ee<4;++ee) h2v[ee] = s_h2[(wave*4+ee)*64 + kc*8+kk];
      #pragma unroll
      for (int p=0;p<NPATHS;++p){
        float wv = s_w3[kk*960 + p*64 + lane];
        #pragma unroll
        for (int ee=0;ee<4;++ee) wgt[p][ee] = fmaf(h2v[ee], wv, wgt[p][ee]);
      }
    }
    __syncthreads();
  }

  // fold envelope * 1/sqrt(avg_nn)
  #pragma unroll
  for (int ee=0;ee<4;++ee){
    float f = s_cut[wave*4+ee] * 0.25f;
    #pragma unroll
    for (int p=0;p<NPATHS;++p) wgt[p][ee] *= f;
  }

  // Phase C: CG tensor product + atomic scatter to receivers
  #pragma unroll
  for (int ee=0;ee<4;++ee){
    const int slot = wave*4 + ee;
    const int e = ebase + slot;
    const int s = senders[e];
    const int r = receivers[e];
    const int sb = s*FPN;
    float X[9], S[9], msg[9];
    X[0] = feats[sb + lane];
    #pragma unroll
    for (int m=0;m<3;++m) X[1+m] = feats[sb + 64  + lane*3 + m];
    #pragma unroll
    for (int m=0;m<5;++m) X[4+m] = feats[sb + 256 + lane*5 + m];
    S[0] = 1.f;
    #pragma unroll
    for (int j=0;j<8;++j) S[1+j] = s_sh[slot][j];
    #pragma unroll
    for (int k=0;k<9;++k) msg[k] = 0.f;

    #pragma unroll
    for (int p=0;p<NPATHS;++p){
      const int l1=PL1[p], l2=PL2[p], l3=PL3[p];
      const int n2=2*l2+1, n3=2*l3+1;
      const float wp = wgt[p][ee];
      #pragma unroll
      for (int i=0;i<2*l1+1;++i){
        #pragma unroll
        for (int j=0;j<n2;++j){
          float t = wp * X[BOFF[l1]+i] * S[BOFF[l2]+j];
          #pragma unroll
          for (int k=0;k<n3;++k)
            msg[BOFF[l3]+k] = fmaf(cg.v[CGOFF[p] + (i*n2+j)*n3 + k], t, msg[BOFF[l3]+k]);
        }
      }
    }

    const int rb = r*FPN;
    unsafeAtomicAdd(&agg[rb + lane], msg[0]);
    #pragma unroll
    for (int m=0;m<3;++m) unsafeAtomicAdd(&agg[rb + 64  + lane*3 + m], msg[1+m]);
    #pragma unroll
    for (int m=0;m<5;++m) unsafeAtomicAdd(&agg[rb + 256 + lane*5 + m], msg[4+m]);
  }
}

// one wave per node: self-interaction linear + silu/gate update
__global__ __launch_bounds__(64) void k_node(
    float* __restrict__ feats, const float* __restrict__ agg,
    const float* __restrict__ lin,   // lin_self for this layer: [3][64][64]
    const float* __restrict__ gw,    // gate_w  for this layer: [2][64][64]
    const float* __restrict__ gb)    // gate_b  for this layer: [2][64]
{
  __shared__ float sf0[64];
  const int n = blockIdx.x, d = threadIdx.x;
  const int base = n*FPN;
  float y[9];
  #pragma unroll
  for (int k=0;k<9;++k) y[k]=0.f;

  for (int c=0;c<64;++c){
    float l0 = lin[          c*64 + d];
    float l1 = lin[4096    + c*64 + d];
    float l2 = lin[8192    + c*64 + d];
    float a0 = agg[base + c];
    y[0] = fmaf(a0, l0, y[0]);
    #pragma unroll
    for (int m=0;m<3;++m) y[1+m] = fmaf(agg[base + 64  + c*3 + m], l1, y[1+m]);
    #pragma unroll
    for (int m=0;m<5;++m) y[4+m] = fmaf(agg[base + 256 + c*5 + m], l2, y[4+m]);
  }

  float f0 = feats[base + d] + siluf(y[0]);
  feats[base + d] = f0;
  sf0[d] = f0;
  __syncthreads();

  // gate for l=1
  {
    float acc = gb[d];
    for (int c=0;c<64;++c) acc = fmaf(sf0[c], gw[c*64 + d], acc);
    float g = sigmf(acc);
    #pragma unroll
    for (int m=0;m<3;++m) feats[base + 64 + d*3 + m] += g*y[1+m];
  }
  // gate for l=2
  {
    float acc = gb[64 + d];
    for (int c=0;c<64;++c) acc = fmaf(sf0[c], gw[4096 + c*64 + d], acc);
    float g = sigmf(acc);
    #pragma unroll
    for (int m=0;m<5;++m) feats[base + 256 + d*5 + m] += g*y[4+m];
  }
}

__global__ __launch_bounds__(256) void k_out(const float* __restrict__ feats,
                                             float* __restrict__ out)
{
  const int n = blockIdx.x;
  for (int j = threadIdx.x; j < FPN; j += 256){
    float sc = (j < 64) ? 1.0f : ((j < 256) ? 0.5f : 0.25f);
    out[n*FPN + j] = feats[n*FPN + j] * sc;
  }
}

// ---------------- launch ----------------
extern "C" void kernel_launch(void* const* d_in, const int* in_sizes, int n_in,
                              void* d_out, int out_size, void* d_ws, size_t ws_size,
                              hipStream_t stream)
{
  const float* pos      = (const float*)d_in[0];
  const int*   species  = (const int*)  d_in[1];
  const int*   senders  = (const int*)  d_in[2];
  const int*   receivers= (const int*)  d_in[3];
  const float* embed    = (const float*)d_in[4];
  const float* wproj    = (const float*)d_in[5];
  const float* w1       = (const float*)d_in[6];
  const float* b1       = (const float*)d_in[7];
  const float* w2       = (const float*)d_in[8];
  const float* b2       = (const float*)d_in[9];
  const float* w3       = (const float*)d_in[10];
  const float* lin      = (const float*)d_in[11];
  const float* gw       = (const float*)d_in[12];
  const float* gb       = (const float*)d_in[13];

  float* feats = (float*)d_ws;
  float* agg   = feats + (size_t)N_NODES*FPN;
  const CGTable& cg = cg_table();

  hipLaunchKernelGGL(k_init, dim3(N_NODES), dim3(64), 0, stream,
                     species, embed, wproj, feats);

  for (int L=0; L<2; ++L){
    hipMemsetAsync(agg, 0, (size_t)N_NODES*FPN*sizeof(float), stream);
    hipLaunchKernelGGL(k_edge, dim3(N_EDGES/16), dim3(256), 0, stream,
                       pos, senders, receivers,
                       w1 + L*8*64, b1 + L*64, w2 + L*64*64, b2 + L*64,
                       w3 + L*64*960,
                       feats, agg, cg);
    hipLaunchKernelGGL(k_node, dim3(N_NODES), dim3(64), 0, stream,
                       feats, agg, lin + L*3*64*64, gw + L*2*64*64, gb + L*2*64);
  }
  hipLaunchKernelGGL(k_out, dim3(N_NODES), dim3(256), 0, stream,
                     feats, (float*)d_out);
}